// Round 14
// baseline (29.880 us; speedup 1.0000x reference)
//
#include <hip/hip_runtime.h>
#include <math.h>

// Problem constants (from reference: x = (2,2,160,160,160) fp32)
#define BCn 4
#define Dn 160
#define Hn 160
#define Wn 160
#define HWn (Hn * Wn)
#define W4q (Wn / 4)        // 40 float4 groups per row
#define COLS (Hn * W4q)     // 6400 (h, q) columns per plane
#define DCHUNK 5
#define NZC (Dn / DCHUNK)   // 32 z-chunks
#define XBLK (COLS / 256)   // 25 x-blocks per work-row
#define BLOCK 256

// Native clang vector type (also used for the plain vector store).
typedef float f32x4 __attribute__((ext_vector_type(4)));

// Reduced per-plane state for 4 consecutive W outputs:
//   Rs = 3x3 window sums (feeds gd), Rd = row(h+1)-row(h-1) sums (feeds gh),
//   Cs = col(w+1)-col(w-1) sums (feeds gw).
struct Plane {
  float4 Rs, Rd, Cs;
};

// One z-plane: 3 coalesced float4 loads; w-halo via neighbor-lane shuffles
// (R6 win: avoids 6 full-wave scalar loads' L1 line-touches).
__device__ __forceinline__ Plane load_plane(const float* __restrict__ xb, int zz,
                                            int rm, int r0, int rp, int w4,
                                            bool ql, bool qr, bool fixL, bool fixR) {
  const int zc = zz < 0 ? 0 : (zz > Dn - 1 ? Dn - 1 : zz);
  const float* p = xb + (size_t)zc * HWn;

  const float4 vm = *(const float4*)(p + rm + w4);
  const float4 v0 = *(const float4*)(p + r0 + w4);
  const float4 vp = *(const float4*)(p + rp + w4);

  float lA = __shfl_up(vm.w, 1);
  float lB = __shfl_up(v0.w, 1);
  float lC = __shfl_up(vp.w, 1);
  float rA = __shfl_down(vm.x, 1);
  float rB = __shfl_down(v0.x, 1);
  float rC = __shfl_down(vp.x, 1);

  if (fixL) {
    lA = p[rm + w4 - 1];
    lB = p[r0 + w4 - 1];
    lC = p[rp + w4 - 1];
  }
  if (fixR) {
    rA = p[rm + w4 + 4];
    rB = p[r0 + w4 + 4];
    rC = p[rp + w4 + 4];
  }

  const float m0 = ql ? vm.x : lA;
  const float c0 = ql ? v0.x : lB;
  const float q0 = ql ? vp.x : lC;
  const float m5 = qr ? vm.w : rA;
  const float c5 = qr ? v0.w : rB;
  const float q5 = qr ? vp.w : rC;

  const float s0 = m0 + c0 + q0;
  const float s1 = vm.x + v0.x + vp.x;
  const float s2 = vm.y + v0.y + vp.y;
  const float s3 = vm.z + v0.z + vp.z;
  const float s4 = vm.w + v0.w + vp.w;
  const float s5 = m5 + c5 + q5;
  const float d0 = q0 - m0;
  const float d1 = vp.x - vm.x;
  const float d2 = vp.y - vm.y;
  const float d3 = vp.z - vm.z;
  const float d4 = vp.w - vm.w;
  const float d5 = q5 - m5;

  Plane out;
  const float t12 = s1 + s2, t23 = s2 + s3, t34 = s3 + s4;
  out.Rs.x = s0 + t12;
  out.Rs.y = t12 + s3;
  out.Rs.z = t23 + s4;
  out.Rs.w = t34 + s5;
  const float u12 = d1 + d2, u23 = d2 + d3, u34 = d3 + d4;
  out.Rd.x = d0 + u12;
  out.Rd.y = u12 + d3;
  out.Rd.z = u23 + d4;
  out.Rd.w = u34 + d5;
  out.Cs.x = s2 - s0;
  out.Cs.y = s3 - s1;
  out.Cs.z = s4 - s2;
  out.Cs.w = s5 - s3;
  return out;
}

__device__ __forceinline__ f32x4 mag4(const Plane& P0, const Plane& P1,
                                      const Plane& P2) {
  const float gdx = P2.Rs.x - P0.Rs.x;
  const float gdy = P2.Rs.y - P0.Rs.y;
  const float gdz = P2.Rs.z - P0.Rs.z;
  const float gdw = P2.Rs.w - P0.Rs.w;
  const float ghx = P0.Rd.x + P1.Rd.x + P2.Rd.x;
  const float ghy = P0.Rd.y + P1.Rd.y + P2.Rd.y;
  const float ghz = P0.Rd.z + P1.Rd.z + P2.Rd.z;
  const float ghw = P0.Rd.w + P1.Rd.w + P2.Rd.w;
  const float gwx = P0.Cs.x + P1.Cs.x + P2.Cs.x;
  const float gwy = P0.Cs.y + P1.Cs.y + P2.Cs.y;
  const float gwz = P0.Cs.z + P1.Cs.z + P2.Cs.z;
  const float gww = P0.Cs.w + P1.Cs.w + P2.Cs.w;
  f32x4 g;
  // Raw v_sqrt_f32 — abs threshold 0.555, libm fixup unnecessary.
  g.x = __builtin_amdgcn_sqrtf(fmaf(gdx, gdx, fmaf(ghx, ghx, gwx * gwx)));
  g.y = __builtin_amdgcn_sqrtf(fmaf(gdy, gdy, fmaf(ghy, ghy, gwy * gwy)));
  g.z = __builtin_amdgcn_sqrtf(fmaf(gdz, gdz, fmaf(ghz, ghz, gwz * gwz)));
  g.w = __builtin_amdgcn_sqrtf(fmaf(gdw, gdw, fmaf(ghw, ghw, gww * gww)));
  return g;
}

__global__ __launch_bounds__(BLOCK) void sobel3d_mag_kernel(
    const float* __restrict__ x, float* __restrict__ out) {
  // XCD-locality swizzle (R9 win: FETCH 61->44.5 MB, bench 35->29 us).
  const int F = blockIdx.x;          // 0..3199
  const int k = F & 7;               // xcd (hw round-robin heuristic)
  const int j = F >> 3;              // 0..399
  const int bx = j % XBLK;           // x-block within work-row
  const int wr = (j / XBLK) * 8 + k; // work-row 0..127, stays on xcd k
  const int zc_idx = wr & (NZC - 1);
  const int bc = wr >> 5;

  const int col4 = bx * BLOCK + threadIdx.x;  // (h, q), 0..6399
  const int h = col4 / W4q;
  const int q = col4 - h * W4q;
  const int w4 = q * 4;
  const int d0 = zc_idx * DCHUNK;

  const float* xb = x + (size_t)bc * Dn * HWn;
  float* ob = out + (size_t)bc * Dn * HWn;

  const int hm = (h > 0) ? h - 1 : 0;
  const int hp = (h < Hn - 1) ? h + 1 : Hn - 1;
  const int rm = hm * Wn;
  const int r0 = h * Wn;
  const int rp = hp * Wn;

  const int lane = threadIdx.x & 63;
  const bool ql = (q == 0);
  const bool qr = (q == W4q - 1);
  const bool fixL = (lane == 0) && !ql;
  const bool fixR = (lane == 63) && !qr;

  Plane P0 = load_plane(xb, d0 - 1, rm, r0, rp, w4, ql, qr, fixL, fixR);
  Plane P1 = load_plane(xb, d0, rm, r0, rp, w4, ql, qr, fixL, fixR);

#pragma unroll
  for (int i = 0; i < DCHUNK; ++i) {
    const int z = d0 + i;
    Plane P2 = load_plane(xb, z + 1, rm, r0, rp, w4, ql, qr, fixL, fixR);
    // A/B vs R9: PLAIN vector store (no nontemporal flag) — the only
    // never-isolated variable left. If nt was forgoing L2 write-combining,
    // this recovers it; if nt was protecting input residency, FETCH rises.
    *(f32x4*)(ob + (size_t)z * HWn + r0 + w4) = mag4(P0, P1, P2);
    P0 = P1;
    P1 = P2;
  }
}

extern "C" void kernel_launch(void* const* d_in, const int* in_sizes, int n_in,
                              void* d_out, int out_size, void* d_ws, size_t ws_size,
                              hipStream_t stream) {
  const float* x = (const float*)d_in[0];
  float* out = (float*)d_out;

  dim3 block(BLOCK);
  dim3 grid(XBLK * NZC * BCn);  // flat 3200 blocks; swizzle decoded in-kernel
  sobel3d_mag_kernel<<<grid, block, 0, stream>>>(x, out);
}

// Round 15
// 28.039 us; speedup vs baseline: 1.0657x; 1.0657x over previous
//
#include <hip/hip_runtime.h>
#include <math.h>

// Problem constants (from reference: x = (2,2,160,160,160) fp32)
#define BCn 4
#define Dn 160
#define Hn 160
#define Wn 160
#define HWn (Hn * Wn)
#define W4q (Wn / 4)        // 40 float4 groups per row
#define COLS (Hn * W4q)     // 6400 (h, q) columns per plane
#define DCHUNK 8            // 4 pair-iterations per chunk
#define NZC (Dn / DCHUNK)   // 20 z-chunks
#define XBLK (COLS / 256)   // 25 x-blocks per work-row
#define NWR (NZC * BCn)     // 80 work-rows; 80 % 8 == 0 (bijective swizzle)
#define BLOCK 256

typedef float f32x4 __attribute__((ext_vector_type(4)));

// Reduced per-plane state:
//   Rs = 3x3 window sums (gd), Rd = row diffs (gh), Cs = col diffs (gw).
struct Plane {
  float4 Rs, Rd, Cs;
};

// One z-plane: 3 coalesced float4 loads; w-halo via neighbor-lane shuffles
// (R6 win). Two of these back-to-back per iteration give 2-deep plane MLP.
__device__ __forceinline__ Plane load_plane(const float* __restrict__ xb, int zz,
                                            int rm, int r0, int rp, int w4,
                                            bool ql, bool qr, bool fixL, bool fixR) {
  const int zc = zz < 0 ? 0 : (zz > Dn - 1 ? Dn - 1 : zz);
  const float* p = xb + (size_t)zc * HWn;

  const float4 vm = *(const float4*)(p + rm + w4);
  const float4 v0 = *(const float4*)(p + r0 + w4);
  const float4 vp = *(const float4*)(p + rp + w4);

  float lA = __shfl_up(vm.w, 1);
  float lB = __shfl_up(v0.w, 1);
  float lC = __shfl_up(vp.w, 1);
  float rA = __shfl_down(vm.x, 1);
  float rB = __shfl_down(v0.x, 1);
  float rC = __shfl_down(vp.x, 1);

  if (fixL) {
    lA = p[rm + w4 - 1];
    lB = p[r0 + w4 - 1];
    lC = p[rp + w4 - 1];
  }
  if (fixR) {
    rA = p[rm + w4 + 4];
    rB = p[r0 + w4 + 4];
    rC = p[rp + w4 + 4];
  }

  const float m0 = ql ? vm.x : lA;
  const float c0 = ql ? v0.x : lB;
  const float q0 = ql ? vp.x : lC;
  const float m5 = qr ? vm.w : rA;
  const float c5 = qr ? v0.w : rB;
  const float q5 = qr ? vp.w : rC;

  const float s0 = m0 + c0 + q0;
  const float s1 = vm.x + v0.x + vp.x;
  const float s2 = vm.y + v0.y + vp.y;
  const float s3 = vm.z + v0.z + vp.z;
  const float s4 = vm.w + v0.w + vp.w;
  const float s5 = m5 + c5 + q5;
  const float d0 = q0 - m0;
  const float d1 = vp.x - vm.x;
  const float d2 = vp.y - vm.y;
  const float d3 = vp.z - vm.z;
  const float d4 = vp.w - vm.w;
  const float d5 = q5 - m5;

  Plane out;
  const float t12 = s1 + s2, t23 = s2 + s3, t34 = s3 + s4;
  out.Rs.x = s0 + t12;
  out.Rs.y = t12 + s3;
  out.Rs.z = t23 + s4;
  out.Rs.w = t34 + s5;
  const float u12 = d1 + d2, u23 = d2 + d3, u34 = d3 + d4;
  out.Rd.x = d0 + u12;
  out.Rd.y = u12 + d3;
  out.Rd.z = u23 + d4;
  out.Rd.w = u34 + d5;
  out.Cs.x = s2 - s0;
  out.Cs.y = s3 - s1;
  out.Cs.z = s4 - s2;
  out.Cs.w = s5 - s3;
  return out;
}

__device__ __forceinline__ f32x4 mag4(const Plane& P0, const Plane& P1,
                                      const Plane& P2) {
  const float gdx = P2.Rs.x - P0.Rs.x;
  const float gdy = P2.Rs.y - P0.Rs.y;
  const float gdz = P2.Rs.z - P0.Rs.z;
  const float gdw = P2.Rs.w - P0.Rs.w;
  const float ghx = P0.Rd.x + P1.Rd.x + P2.Rd.x;
  const float ghy = P0.Rd.y + P1.Rd.y + P2.Rd.y;
  const float ghz = P0.Rd.z + P1.Rd.z + P2.Rd.z;
  const float ghw = P0.Rd.w + P1.Rd.w + P2.Rd.w;
  const float gwx = P0.Cs.x + P1.Cs.x + P2.Cs.x;
  const float gwy = P0.Cs.y + P1.Cs.y + P2.Cs.y;
  const float gwz = P0.Cs.z + P1.Cs.z + P2.Cs.z;
  const float gww = P0.Cs.w + P1.Cs.w + P2.Cs.w;
  f32x4 g;
  // Raw v_sqrt_f32 — abs threshold 0.555, libm fixup unnecessary.
  g.x = __builtin_amdgcn_sqrtf(fmaf(gdx, gdx, fmaf(ghx, ghx, gwx * gwx)));
  g.y = __builtin_amdgcn_sqrtf(fmaf(gdy, gdy, fmaf(ghy, ghy, gwy * gwy)));
  g.z = __builtin_amdgcn_sqrtf(fmaf(gdz, gdz, fmaf(ghz, ghz, gwz * gwz)));
  g.w = __builtin_amdgcn_sqrtf(fmaf(gdw, gdw, fmaf(ghw, ghw, gww * gww)));
  return g;
}

__global__ __launch_bounds__(BLOCK) void sobel3d_mag_kernel(
    const float* __restrict__ x, float* __restrict__ out) {
  // XCD-locality swizzle (R9 win): all 25 x-blocks of a work-row
  // (z-chunk, channel) share one XCD.
  const int F = blockIdx.x;          // 0..1999
  const int k = F & 7;               // xcd (hw round-robin heuristic)
  const int j = F >> 3;              // 0..249
  const int bx = j % XBLK;           // x-block within work-row
  const int wr = (j / XBLK) * 8 + k; // work-row 0..79, stays on xcd k
  const int zc_idx = wr % NZC;       // 20 z-chunks
  const int bc = wr / NZC;           // channel 0..3

  const int col4 = bx * BLOCK + threadIdx.x;  // (h, q), 0..6399
  const int h = col4 / W4q;
  const int q = col4 - h * W4q;
  const int w4 = q * 4;
  const int d0 = zc_idx * DCHUNK;

  const float* xb = x + (size_t)bc * Dn * HWn;
  float* ob = out + (size_t)bc * Dn * HWn;

  const int hm = (h > 0) ? h - 1 : 0;
  const int hp = (h < Hn - 1) ? h + 1 : Hn - 1;
  const int rm = hm * Wn;
  const int r0 = h * Wn;
  const int rp = hp * Wn;

  const int lane = threadIdx.x & 63;
  const bool ql = (q == 0);
  const bool qr = (q == W4q - 1);
  const bool fixL = (lane == 0) && !ql;
  const bool fixR = (lane == 63) && !qr;

  // Window: P0 = plane z-1, P1 = plane z.
  Plane P0 = load_plane(xb, d0 - 1, rm, r0, rp, w4, ql, qr, fixL, fixR);
  Plane P1 = load_plane(xb, d0, rm, r0, rp, w4, ql, qr, fixL, fixR);

#pragma unroll
  for (int i = 0; i < DCHUNK / 2; ++i) {
    const int z = d0 + 2 * i;
    // Two INDEPENDENT plane-load groups issued back-to-back: 2-deep memory
    // parallelism per wave (the rolling-by-1 window only ever had 1).
    Plane P2 = load_plane(xb, z + 1, rm, r0, rp, w4, ql, qr, fixL, fixR);
    Plane P3 = load_plane(xb, z + 2, rm, r0, rp, w4, ql, qr, fixL, fixR);
    *(f32x4*)(ob + (size_t)z * HWn + r0 + w4) = mag4(P0, P1, P2);
    *(f32x4*)(ob + (size_t)(z + 1) * HWn + r0 + w4) = mag4(P1, P2, P3);
    P0 = P2;
    P1 = P3;
  }
}

extern "C" void kernel_launch(void* const* d_in, const int* in_sizes, int n_in,
                              void* d_out, int out_size, void* d_ws, size_t ws_size,
                              hipStream_t stream) {
  const float* x = (const float*)d_in[0];
  float* out = (float*)d_out;

  dim3 block(BLOCK);
  dim3 grid(XBLK * NWR);  // flat 2000 blocks; swizzle decoded in-kernel
  sobel3d_mag_kernel<<<grid, block, 0, stream>>>(x, out);
}